// Round 2
// baseline (72.588 us; speedup 1.0000x reference)
//
#include <hip/hip_runtime.h>

typedef __attribute__((ext_vector_type(8))) __bf16 bf16x8;
typedef __attribute__((ext_vector_type(4))) float f32x4;
typedef __attribute__((ext_vector_type(4))) unsigned int u32x4;
typedef __attribute__((ext_vector_type(4))) unsigned short u16x4;

// LDS layout (bytes). xq region triple-duty: X(bf16) -> Q(bf16) -> P(bf16).
#define LDS_XQ   0         // 256 rows * 128B   = 32768
#define LDS_W    32768     // 3 * 64 rows *128B = 24576
#define LDS_K    57344     // 256 rows * 128B   = 32768
#define LDS_VT   90112     // 64 rows * 512B    = 32768 (V transposed: [h][key])
#define LDS_BIAS 122880    // 192 floats        = 768
#define LDS_TOT  123648

static __device__ __forceinline__ unsigned short f2bf(float f) {
  unsigned int u = __builtin_bit_cast(unsigned int, f);
  u += 0x7fffu + ((u >> 16) & 1u);           // round-to-nearest-even
  return (unsigned short)(u >> 16);
}
// XOR-swizzle: spreads stride-128B/512B row-major column reads across banks.
static __device__ __forceinline__ int swz128(int row, int colbyte) {
  return row * 128 + (colbyte ^ ((row & 7) << 4));
}
static __device__ __forceinline__ int swz512(int row, int colbyte) {
  return row * 512 + (colbyte ^ ((row & 7) << 4));
}

__global__ __launch_bounds__(512, 2)
void head_fused(const float* __restrict__ x,
                const float* __restrict__ Wq, const float* __restrict__ bq,
                const float* __restrict__ Wk, const float* __restrict__ bk,
                const float* __restrict__ Wv, const float* __restrict__ bv,
                float* __restrict__ out)
{
  __shared__ __align__(16) char smem[LDS_TOT];
  const int b    = blockIdx.x;
  const int tid  = threadIdx.x;
  const int lane = tid & 63;
  const int wid  = tid >> 6;      // 8 waves
  const int g    = lane >> 4;     // 4 quarter-wave groups
  const int ln   = lane & 15;

  // ---------------- Phase 0: stage X, W (bf16) + biases (f32) into LDS ----
  {
    const float4* xg = (const float4*)(x + (size_t)b * (256 * 64));
#pragma unroll
    for (int i = 0; i < 8; ++i) {
      int idx = tid + i * 512;               // 4096 float4 total
      float4 v = xg[idx];
      int e = idx * 4;
      int t = e >> 6, c = e & 63;            // c multiple of 4
      u16x4 p;
      p.x = f2bf(v.x); p.y = f2bf(v.y); p.z = f2bf(v.z); p.w = f2bf(v.w);
      *(u16x4*)(smem + LDS_XQ + swz128(t, c * 2)) = p;
    }
#pragma unroll
    for (int i = 0; i < 6; ++i) {
      int idx = tid + i * 512;               // 3072 float4 total (3 matrices)
      int mat = idx >> 10;
      int rem = idx & 1023;
      const float4* wg = (const float4*)(mat == 0 ? Wq : (mat == 1 ? Wk : Wv));
      float4 v = wg[rem];
      int e = rem * 4;
      int h = e >> 6, c = e & 63;
      u16x4 p;
      p.x = f2bf(v.x); p.y = f2bf(v.y); p.z = f2bf(v.z); p.w = f2bf(v.w);
      *(u16x4*)(smem + LDS_W + mat * 8192 + swz128(h, c * 2)) = p;
    }
    if (tid < 192) {
      float v = (tid < 64) ? bq[tid] : (tid < 128) ? bk[tid - 64] : bv[tid - 128];
      ((float*)(smem + LDS_BIAS))[tid] = v;
    }
  }
  __syncthreads();

  // ---------------- Phase 1: projections (each wave owns 32 rows) ---------
  const int rowbase = wid * 32;

  // X fragments for own rows: serve as A (for V) and as B (for Q^T,K^T).
  bf16x8 xf[2][2];
#pragma unroll
  for (int tt = 0; tt < 2; ++tt)
#pragma unroll
    for (int ks = 0; ks < 2; ++ks) {
      int t = rowbase + tt * 16 + ln;
      u32x4 u = *(const u32x4*)(smem + LDS_XQ + swz128(t, (ks * 32 + g * 8) * 2));
      xf[tt][ks] = __builtin_bit_cast(bf16x8, u);
    }

  // Q and K via W·X^T: acc D[h][t] -> contiguous b64 stores of row-major [t][h].
#pragma unroll
  for (int m = 0; m < 2; ++m) {              // 0 -> Q (scaled 1/8), 1 -> K
    const int wb = LDS_W + m * 8192;
#pragma unroll
    for (int mt = 0; mt < 4; ++mt) {
      float4 bb = *(const float4*)(smem + LDS_BIAS + (m * 64 + mt * 16 + g * 4) * 4);
#pragma unroll
      for (int tt = 0; tt < 2; ++tt) {
        f32x4 acc = {0.f, 0.f, 0.f, 0.f};
#pragma unroll
        for (int ks = 0; ks < 2; ++ks) {
          int h = mt * 16 + ln;
          u32x4 u = *(const u32x4*)(smem + wb + swz128(h, (ks * 32 + g * 8) * 2));
          acc = __builtin_amdgcn_mfma_f32_16x16x32_bf16(
                  __builtin_bit_cast(bf16x8, u), xf[tt][ks], acc, 0, 0, 0);
        }
        int t  = rowbase + tt * 16 + ln;
        int h0 = mt * 16 + g * 4;
        float s = (m == 0) ? 0.125f : 1.0f;
        u16x4 p;
        p.x = f2bf((acc[0] + bb.x) * s);
        p.y = f2bf((acc[1] + bb.y) * s);
        p.z = f2bf((acc[2] + bb.z) * s);
        p.w = f2bf((acc[3] + bb.w) * s);
        char* dst = smem + ((m == 0) ? LDS_XQ : LDS_K);  // Q overwrites X rows
        *(u16x4*)(dst + swz128(t, h0 * 2)) = p;
      }
    }
  }

  // V via X·Wv^T: acc D[t][h] -> contiguous b64 stores of transposed Vt[h][t].
#pragma unroll
  for (int nf = 0; nf < 4; ++nf) {
    int h = nf * 16 + ln;
    float bvv = ((const float*)(smem + LDS_BIAS))[128 + h];
#pragma unroll
    for (int tt = 0; tt < 2; ++tt) {
      f32x4 acc = {0.f, 0.f, 0.f, 0.f};
#pragma unroll
      for (int ks = 0; ks < 2; ++ks) {
        u32x4 u = *(const u32x4*)(smem + LDS_W + 2 * 8192 + swz128(h, (ks * 32 + g * 8) * 2));
        acc = __builtin_amdgcn_mfma_f32_16x16x32_bf16(
                xf[tt][ks], __builtin_bit_cast(bf16x8, u), acc, 0, 0, 0);
      }
      int t0 = rowbase + tt * 16 + g * 4;
      u16x4 p;
      p.x = f2bf(acc[0] + bvv); p.y = f2bf(acc[1] + bvv);
      p.z = f2bf(acc[2] + bvv); p.w = f2bf(acc[3] + bvv);
      *(u16x4*)(smem + LDS_VT + swz512(h, t0 * 2)) = p;
    }
  }
  __syncthreads();

  // ---------------- Phase 2: flash attention (wave w: rows [32w,32w+32)) --
  bf16x8 qa[2][2];
#pragma unroll
  for (int mt = 0; mt < 2; ++mt)
#pragma unroll
    for (int ks = 0; ks < 2; ++ks) {
      int t = rowbase + mt * 16 + ln;
      u32x4 u = *(const u32x4*)(smem + LDS_XQ + swz128(t, (ks * 32 + g * 8) * 2));
      qa[mt][ks] = __builtin_bit_cast(bf16x8, u);
    }

  float mrun[2][4], lrun[2][4];
  f32x4 oacc[2][4];
#pragma unroll
  for (int mt = 0; mt < 2; ++mt)
#pragma unroll
    for (int r = 0; r < 4; ++r) {
      mrun[mt][r] = -1e30f; lrun[mt][r] = 0.f;
    }
#pragma unroll
  for (int mt = 0; mt < 2; ++mt)
#pragma unroll
    for (int nf = 0; nf < 4; ++nf)
      oacc[mt][nf] = (f32x4){0.f, 0.f, 0.f, 0.f};

  const int jmax = (rowbase + 31) >> 6;
  for (int jt = 0; jt <= jmax; ++jt) {
    // S = Q·K^T (scale pre-folded into Q)
    f32x4 s[2][4];
#pragma unroll
    for (int mt = 0; mt < 2; ++mt)
#pragma unroll
      for (int nk = 0; nk < 4; ++nk)
        s[mt][nk] = (f32x4){0.f, 0.f, 0.f, 0.f};
#pragma unroll
    for (int ks = 0; ks < 2; ++ks) {
      bf16x8 kb[4];
#pragma unroll
      for (int nk = 0; nk < 4; ++nk) {
        int key = jt * 64 + nk * 16 + ln;
        u32x4 u = *(const u32x4*)(smem + LDS_K + swz128(key, (ks * 32 + g * 8) * 2));
        kb[nk] = __builtin_bit_cast(bf16x8, u);
      }
#pragma unroll
      for (int mt = 0; mt < 2; ++mt)
#pragma unroll
        for (int nk = 0; nk < 4; ++nk)
          s[mt][nk] = __builtin_amdgcn_mfma_f32_16x16x32_bf16(qa[mt][ks], kb[nk], s[mt][nk], 0, 0, 0);
    }
    // causal mask: only the diagonal tile is partial (64*jmax <= rowbase)
    if (jt == jmax) {
#pragma unroll
      for (int mt = 0; mt < 2; ++mt)
#pragma unroll
        for (int nk = 0; nk < 4; ++nk) {
          int key = jt * 64 + nk * 16 + ln;
#pragma unroll
          for (int r = 0; r < 4; ++r) {
            int t = rowbase + mt * 16 + g * 4 + r;
            if (key > t) s[mt][nk][r] = -1e30f;
          }
        }
    }
    // online softmax + P->LDS (bf16) + rescale O
#pragma unroll
    for (int mt = 0; mt < 2; ++mt) {
      float al[4];
#pragma unroll
      for (int r = 0; r < 4; ++r) {
        float mx = fmaxf(fmaxf(s[mt][0][r], s[mt][1][r]), fmaxf(s[mt][2][r], s[mt][3][r]));
        mx = fmaxf(mx, __shfl_xor(mx, 1));
        mx = fmaxf(mx, __shfl_xor(mx, 2));
        mx = fmaxf(mx, __shfl_xor(mx, 4));
        mx = fmaxf(mx, __shfl_xor(mx, 8));
        float mn = fmaxf(mrun[mt][r], mx);
        float a  = __expf(mrun[mt][r] - mn);
        mrun[mt][r] = mn;
        float sum = 0.f;
#pragma unroll
        for (int nk = 0; nk < 4; ++nk) {
          float p = __expf(s[mt][nk][r] - mn);
          s[mt][nk][r] = p;
          sum += p;
        }
        sum += __shfl_xor(sum, 1);
        sum += __shfl_xor(sum, 2);
        sum += __shfl_xor(sum, 4);
        sum += __shfl_xor(sum, 8);
        lrun[mt][r] = lrun[mt][r] * a + sum;
        al[r] = a;
      }
#pragma unroll
      for (int nf = 0; nf < 4; ++nf)
#pragma unroll
        for (int r = 0; r < 4; ++r)
          oacc[mt][nf][r] *= al[r];
      // P tile store (wave-private region = own Q rows, now dead)
#pragma unroll
      for (int nk = 0; nk < 4; ++nk)
#pragma unroll
        for (int r = 0; r < 4; ++r) {
          int t = rowbase + mt * 16 + g * 4 + r;
          *(unsigned short*)(smem + LDS_XQ + swz128(t, (nk * 16 + ln) * 2)) = f2bf(s[mt][nk][r]);
        }
    }
    // O += P·V
#pragma unroll
    for (int ks = 0; ks < 2; ++ks) {
      bf16x8 pa[2];
#pragma unroll
      for (int mt = 0; mt < 2; ++mt) {
        int t = rowbase + mt * 16 + ln;
        u32x4 u = *(const u32x4*)(smem + LDS_XQ + swz128(t, (ks * 32 + g * 8) * 2));
        pa[mt] = __builtin_bit_cast(bf16x8, u);
      }
      bf16x8 vb[4];
#pragma unroll
      for (int nf = 0; nf < 4; ++nf) {
        int h = nf * 16 + ln;
        int key0 = jt * 64 + ks * 32 + g * 8;
        u32x4 u = *(const u32x4*)(smem + LDS_VT + swz512(h, key0 * 2));
        vb[nf] = __builtin_bit_cast(bf16x8, u);
      }
#pragma unroll
      for (int mt = 0; mt < 2; ++mt)
#pragma unroll
        for (int nf = 0; nf < 4; ++nf)
          oacc[mt][nf] = __builtin_amdgcn_mfma_f32_16x16x32_bf16(pa[mt], vb[nf], oacc[mt][nf], 0, 0, 0);
    }
  }

  // ---------------- Epilogue: O /= l, store fp32 --------------------------
  float* og = out + (size_t)b * (256 * 64);
#pragma unroll
  for (int mt = 0; mt < 2; ++mt) {
    float inv[4];
#pragma unroll
    for (int r = 0; r < 4; ++r) inv[r] = 1.0f / lrun[mt][r];
#pragma unroll
    for (int nf = 0; nf < 4; ++nf)
#pragma unroll
      for (int r = 0; r < 4; ++r) {
        int t = rowbase + mt * 16 + g * 4 + r;
        og[t * 64 + nf * 16 + ln] = oacc[mt][nf][r] * inv[r];
      }
  }
}

extern "C" void kernel_launch(void* const* d_in, const int* in_sizes, int n_in,
                              void* d_out, int out_size, void* d_ws, size_t ws_size,
                              hipStream_t stream) {
  (void)in_sizes; (void)n_in; (void)d_ws; (void)ws_size; (void)out_size;
  const float* x  = (const float*)d_in[0];
  const float* Wq = (const float*)d_in[1];
  const float* bq = (const float*)d_in[2];
  const float* Wk = (const float*)d_in[3];
  const float* bk = (const float*)d_in[4];
  const float* Wv = (const float*)d_in[5];
  const float* bv = (const float*)d_in[6];
  float* out = (float*)d_out;
  hipLaunchKernelGGL(head_fused, dim3(1024), dim3(512), 0, stream,
                     x, Wq, bq, Wk, bk, Wv, bv, out);
}

// Round 3
// 54.145 us; speedup vs baseline: 1.3406x; 1.3406x over previous
//
#include <hip/hip_runtime.h>

typedef __attribute__((ext_vector_type(8))) __bf16 bf16x8;
typedef __attribute__((ext_vector_type(4))) float f32x4;
typedef __attribute__((ext_vector_type(4))) unsigned int u32x4;
typedef __attribute__((ext_vector_type(2))) unsigned int u32x2;

// LDS layout (bytes). xq region triple-duty: X(bf16) -> Q(bf16) -> P(bf16).
#define LDS_XQ   0         // 256 rows * 128B   = 32768
#define LDS_W    32768     // 3 * 64 rows *128B = 24576
#define LDS_K    57344     // 256 rows * 128B   = 32768
#define LDS_VT   90112     // 64 rows * 512B    = 32768 (V transposed: [h][key])
#define LDS_BIAS 122880    // 192 floats        = 768
#define LDS_TOT  123648

// v_cvt_pk_bf16_f32: dst.lo = bf16(a), dst.hi = bf16(b)
static __device__ __forceinline__ unsigned int cvt_pk_bf16(float a, float b) {
  unsigned int r;
  asm("v_cvt_pk_bf16_f32 %0, %1, %2" : "=v"(r) : "v"(a), "v"(b));
  return r;
}
// XOR-swizzle: spreads stride-128B/512B row-major column reads across banks.
static __device__ __forceinline__ int swz128(int row, int colbyte) {
  return row * 128 + (colbyte ^ ((row & 7) << 4));
}
static __device__ __forceinline__ int swz512(int row, int colbyte) {
  return row * 512 + (colbyte ^ ((row & 7) << 4));
}

__global__ __launch_bounds__(512, 2)
void head_fused(const float* __restrict__ x,
                const float* __restrict__ Wq, const float* __restrict__ bq,
                const float* __restrict__ Wk, const float* __restrict__ bk,
                const float* __restrict__ Wv, const float* __restrict__ bv,
                float* __restrict__ out)
{
  __shared__ __align__(16) char smem[LDS_TOT];
  const int b    = blockIdx.x;
  const int tid  = threadIdx.x;
  const int lane = tid & 63;
  const int wid  = tid >> 6;      // 8 waves
  const int g    = lane >> 4;     // 4 quarter-wave groups
  const int ln   = lane & 15;

  // ---------------- Phase 0: stage X, W (bf16) + biases (f32) into LDS ----
  {
    const float4* xg = (const float4*)(x + (size_t)b * (256 * 64));
#pragma unroll
    for (int i = 0; i < 8; ++i) {
      int idx = tid + i * 512;               // 4096 float4 total
      float4 v = xg[idx];
      int e = idx * 4;
      int t = e >> 6, c = e & 63;            // c multiple of 4
      u32x2 p;
      p.x = cvt_pk_bf16(v.x, v.y);
      p.y = cvt_pk_bf16(v.z, v.w);
      *(u32x2*)(smem + LDS_XQ + swz128(t, c * 2)) = p;
    }
#pragma unroll
    for (int i = 0; i < 6; ++i) {
      int idx = tid + i * 512;               // 3072 float4 total (3 matrices)
      int mat = idx >> 10;
      int rem = idx & 1023;
      const float4* wg = (const float4*)(mat == 0 ? Wq : (mat == 1 ? Wk : Wv));
      float4 v = wg[rem];
      int e = rem * 4;
      int h = e >> 6, c = e & 63;
      u32x2 p;
      p.x = cvt_pk_bf16(v.x, v.y);
      p.y = cvt_pk_bf16(v.z, v.w);
      *(u32x2*)(smem + LDS_W + mat * 8192 + swz128(h, c * 2)) = p;
    }
    if (tid < 192) {
      float v = (tid < 64) ? bq[tid] : (tid < 128) ? bk[tid - 64] : bv[tid - 128];
      ((float*)(smem + LDS_BIAS))[tid] = v;
    }
  }
  __syncthreads();

  // ---------------- Phase 1: projections (each wave owns 32 rows) ---------
  const int rowbase = wid * 32;

  // X fragments for own rows: serve as A (for V) and as B (for Q^T,K^T).
  bf16x8 xf[2][2];
#pragma unroll
  for (int tt = 0; tt < 2; ++tt)
#pragma unroll
    for (int ks = 0; ks < 2; ++ks) {
      int t = rowbase + tt * 16 + ln;
      u32x4 u = *(const u32x4*)(smem + LDS_XQ + swz128(t, (ks * 32 + g * 8) * 2));
      xf[tt][ks] = __builtin_bit_cast(bf16x8, u);
    }

  // Q and K via W·X^T: acc D[h][t] -> contiguous b64 stores of row-major [t][h].
#pragma unroll
  for (int m = 0; m < 2; ++m) {              // 0 -> Q (scaled 1/8), 1 -> K
    const int wb = LDS_W + m * 8192;
#pragma unroll
    for (int mt = 0; mt < 4; ++mt) {
      float4 bb = *(const float4*)(smem + LDS_BIAS + (m * 64 + mt * 16 + g * 4) * 4);
#pragma unroll
      for (int tt = 0; tt < 2; ++tt) {
        f32x4 acc = {0.f, 0.f, 0.f, 0.f};
#pragma unroll
        for (int ks = 0; ks < 2; ++ks) {
          int h = mt * 16 + ln;
          u32x4 u = *(const u32x4*)(smem + wb + swz128(h, (ks * 32 + g * 8) * 2));
          acc = __builtin_amdgcn_mfma_f32_16x16x32_bf16(
                  __builtin_bit_cast(bf16x8, u), xf[tt][ks], acc, 0, 0, 0);
        }
        int t  = rowbase + tt * 16 + ln;
        int h0 = mt * 16 + g * 4;
        float s = (m == 0) ? 0.125f : 1.0f;
        u32x2 p;
        p.x = cvt_pk_bf16((acc[0] + bb.x) * s, (acc[1] + bb.y) * s);
        p.y = cvt_pk_bf16((acc[2] + bb.z) * s, (acc[3] + bb.w) * s);
        char* dst = smem + ((m == 0) ? LDS_XQ : LDS_K);  // Q overwrites X rows
        *(u32x2*)(dst + swz128(t, h0 * 2)) = p;
      }
    }
  }

  // V via X·Wv^T: acc D[t][h] -> contiguous b64 stores of transposed Vt[h][t].
#pragma unroll
  for (int nf = 0; nf < 4; ++nf) {
    int h = nf * 16 + ln;
    float bvv = ((const float*)(smem + LDS_BIAS))[128 + h];
#pragma unroll
    for (int tt = 0; tt < 2; ++tt) {
      f32x4 acc = {0.f, 0.f, 0.f, 0.f};
#pragma unroll
      for (int ks = 0; ks < 2; ++ks) {
        u32x4 u = *(const u32x4*)(smem + LDS_W + 2 * 8192 + swz128(h, (ks * 32 + g * 8) * 2));
        acc = __builtin_amdgcn_mfma_f32_16x16x32_bf16(
                xf[tt][ks], __builtin_bit_cast(bf16x8, u), acc, 0, 0, 0);
      }
      int t0 = rowbase + tt * 16 + g * 4;
      u32x2 p;
      p.x = cvt_pk_bf16(acc[0] + bvv, acc[1] + bvv);
      p.y = cvt_pk_bf16(acc[2] + bvv, acc[3] + bvv);
      *(u32x2*)(smem + LDS_VT + swz512(h, t0 * 2)) = p;
    }
  }
  __syncthreads();

  // ---------------- Phase 2: flash attention (wave w: rows [32w,32w+32)) --
  // Swapped QK^T: S = mfma(K, Q) -> lane owns q-row (q = ln per mt-tile),
  // 16 key-scores in-register; softmax reduce = in-lane + 2 shuffles.
  bf16x8 qa[2][2];
#pragma unroll
  for (int mt = 0; mt < 2; ++mt)
#pragma unroll
    for (int ks = 0; ks < 2; ++ks) {
      int t = rowbase + mt * 16 + ln;
      u32x4 u = *(const u32x4*)(smem + LDS_XQ + swz128(t, (ks * 32 + g * 8) * 2));
      qa[mt][ks] = __builtin_bit_cast(bf16x8, u);
    }

  float mrun[2], lrun[2];
  f32x4 oacc[2][4];
#pragma unroll
  for (int mt = 0; mt < 2; ++mt) { mrun[mt] = -1e30f; lrun[mt] = 0.f; }
#pragma unroll
  for (int mt = 0; mt < 2; ++mt)
#pragma unroll
    for (int nf = 0; nf < 4; ++nf)
      oacc[mt][nf] = (f32x4){0.f, 0.f, 0.f, 0.f};

  const int jmax = (rowbase + 31) >> 6;
  for (int jt = 0; jt <= jmax; ++jt) {
    // S = K·Q^T (scale pre-folded into Q): s[mt][nk][d] = S[key][q],
    // key = jt*64 + nk*16 + g*4 + d, q = rowbase + mt*16 + ln.
    f32x4 s[2][4];
#pragma unroll
    for (int mt = 0; mt < 2; ++mt)
#pragma unroll
      for (int nk = 0; nk < 4; ++nk)
        s[mt][nk] = (f32x4){0.f, 0.f, 0.f, 0.f};
#pragma unroll
    for (int ks = 0; ks < 2; ++ks) {
      bf16x8 kb[4];
#pragma unroll
      for (int nk = 0; nk < 4; ++nk) {
        int key = jt * 64 + nk * 16 + ln;
        u32x4 u = *(const u32x4*)(smem + LDS_K + swz128(key, (ks * 32 + g * 8) * 2));
        kb[nk] = __builtin_bit_cast(bf16x8, u);
      }
#pragma unroll
      for (int mt = 0; mt < 2; ++mt)
#pragma unroll
        for (int nk = 0; nk < 4; ++nk)
          s[mt][nk] = __builtin_amdgcn_mfma_f32_16x16x32_bf16(kb[nk], qa[mt][ks], s[mt][nk], 0, 0, 0);
    }
    // causal mask: only the diagonal tile is partial
    if (jt == jmax) {
#pragma unroll
      for (int mt = 0; mt < 2; ++mt) {
        int q_abs = rowbase + mt * 16 + ln;
#pragma unroll
        for (int nk = 0; nk < 4; ++nk) {
          int keybase = jt * 64 + nk * 16 + g * 4;
#pragma unroll
          for (int d = 0; d < 4; ++d)
            s[mt][nk][d] = (keybase + d > q_abs) ? -1e30f : s[mt][nk][d];
        }
      }
    }
    // online softmax: per-lane scalar state (lane owns q-row = ln)
#pragma unroll
    for (int mt = 0; mt < 2; ++mt) {
      f32x4 m4 = s[mt][0];
#pragma unroll
      for (int d = 0; d < 4; ++d)
        m4[d] = fmaxf(fmaxf(s[mt][0][d], s[mt][1][d]), fmaxf(s[mt][2][d], s[mt][3][d]));
      float mx = fmaxf(fmaxf(m4[0], m4[1]), fmaxf(m4[2], m4[3]));
      mx = fmaxf(mx, __shfl_xor(mx, 16));
      mx = fmaxf(mx, __shfl_xor(mx, 32));
      float mn = fmaxf(mrun[mt], mx);
      float a  = __expf(mrun[mt] - mn);
      mrun[mt] = mn;
      float sum = 0.f;
#pragma unroll
      for (int nk = 0; nk < 4; ++nk)
#pragma unroll
        for (int d = 0; d < 4; ++d) {
          float p = __expf(s[mt][nk][d] - mn);
          s[mt][nk][d] = p;
          sum += p;
        }
      sum += __shfl_xor(sum, 16);
      sum += __shfl_xor(sum, 32);
      lrun[mt] = lrun[mt] * a + sum;
      // rescale O: oacc rows are q = g*4+d -> fetch that row's factor
#pragma unroll
      for (int d = 0; d < 4; ++d) {
        float ad = __shfl(a, g * 4 + d);
#pragma unroll
        for (int nf = 0; nf < 4; ++nf)
          oacc[mt][nf][d] *= ad;
      }
      // P store: key-contiguous in-lane -> packed b64 per (mt,nk)
#pragma unroll
      for (int nk = 0; nk < 4; ++nk) {
        u32x2 p;
        p.x = cvt_pk_bf16(s[mt][nk][0], s[mt][nk][1]);
        p.y = cvt_pk_bf16(s[mt][nk][2], s[mt][nk][3]);
        *(u32x2*)(smem + LDS_XQ + swz128(rowbase + mt * 16 + ln, (nk * 16 + g * 4) * 2)) = p;
      }
    }
    // O += P·V
#pragma unroll
    for (int ks = 0; ks < 2; ++ks) {
      bf16x8 pa[2];
#pragma unroll
      for (int mt = 0; mt < 2; ++mt) {
        int t = rowbase + mt * 16 + ln;
        u32x4 u = *(const u32x4*)(smem + LDS_XQ + swz128(t, (ks * 32 + g * 8) * 2));
        pa[mt] = __builtin_bit_cast(bf16x8, u);
      }
      bf16x8 vb[4];
#pragma unroll
      for (int nf = 0; nf < 4; ++nf) {
        int h = nf * 16 + ln;
        int key0 = jt * 64 + ks * 32 + g * 8;
        u32x4 u = *(const u32x4*)(smem + LDS_VT + swz512(h, key0 * 2));
        vb[nf] = __builtin_bit_cast(bf16x8, u);
      }
#pragma unroll
      for (int mt = 0; mt < 2; ++mt)
#pragma unroll
        for (int nf = 0; nf < 4; ++nf)
          oacc[mt][nf] = __builtin_amdgcn_mfma_f32_16x16x32_bf16(pa[mt], vb[nf], oacc[mt][nf], 0, 0, 0);
    }
  }

  // ---------------- Epilogue: O /= l, store fp32 --------------------------
  float* og = out + (size_t)b * (256 * 64);
#pragma unroll
  for (int mt = 0; mt < 2; ++mt) {
    float linv = 1.0f / lrun[mt];
    float inv[4];
#pragma unroll
    for (int d = 0; d < 4; ++d) inv[d] = __shfl(linv, g * 4 + d);
#pragma unroll
    for (int nf = 0; nf < 4; ++nf)
#pragma unroll
      for (int d = 0; d < 4; ++d) {
        int t = rowbase + mt * 16 + g * 4 + d;
        og[t * 64 + nf * 16 + ln] = oacc[mt][nf][d] * inv[d];
      }
  }
}

extern "C" void kernel_launch(void* const* d_in, const int* in_sizes, int n_in,
                              void* d_out, int out_size, void* d_ws, size_t ws_size,
                              hipStream_t stream) {
  (void)in_sizes; (void)n_in; (void)d_ws; (void)ws_size; (void)out_size;
  const float* x  = (const float*)d_in[0];
  const float* Wq = (const float*)d_in[1];
  const float* bq = (const float*)d_in[2];
  const float* Wk = (const float*)d_in[3];
  const float* bk = (const float*)d_in[4];
  const float* Wv = (const float*)d_in[5];
  const float* bv = (const float*)d_in[6];
  float* out = (float*)d_out;
  hipLaunchKernelGGL(head_fused, dim3(1024), dim3(512), 0, stream,
                     x, Wq, bq, Wk, bk, Wv, bv, out);
}

// Round 4
// 49.003 us; speedup vs baseline: 1.4813x; 1.1049x over previous
//
#include <hip/hip_runtime.h>

typedef __attribute__((ext_vector_type(8))) __bf16 bf16x8;
typedef __attribute__((ext_vector_type(4))) float f32x4;
typedef __attribute__((ext_vector_type(4))) unsigned int u32x4;
typedef __attribute__((ext_vector_type(2))) unsigned int u32x2;

// LDS layout (bytes). xq region triple-duty: X(bf16) -> Q(bf16) -> P(bf16).
#define LDS_XQ   0         // 256 rows * 128B   = 32768
#define LDS_W    32768     // 3 * 64 rows *128B = 24576
#define LDS_K    57344     // 256 rows * 128B   = 32768
#define LDS_VT   90112     // 64 rows * 512B    = 32768 (V transposed: [h][key])
#define LDS_BIAS 122880    // 192 floats        = 768
#define LDS_TOT  123648

// v_cvt_pk_bf16_f32: dst.lo = bf16(a), dst.hi = bf16(b)
static __device__ __forceinline__ unsigned int cvt_pk_bf16(float a, float b) {
  unsigned int r;
  asm("v_cvt_pk_bf16_f32 %0, %1, %2" : "=v"(r) : "v"(a), "v"(b));
  return r;
}
// XOR-swizzle: spreads stride-128B/512B row-major column reads across banks.
static __device__ __forceinline__ int swz128(int row, int colbyte) {
  return row * 128 + (colbyte ^ ((row & 7) << 4));
}
static __device__ __forceinline__ int swz512(int row, int colbyte) {
  return row * 512 + (colbyte ^ ((row & 7) << 4));
}

// 1024 threads = 16 waves/block, each wave owns 16 query rows.
// 123 KB LDS -> 1 block/CU, but 16 waves = 4 waves/SIMD (was 2).
__global__ __launch_bounds__(1024, 4)
void head_fused(const float* __restrict__ x,
                const float* __restrict__ Wq, const float* __restrict__ bq,
                const float* __restrict__ Wk, const float* __restrict__ bk,
                const float* __restrict__ Wv, const float* __restrict__ bv,
                float* __restrict__ out)
{
  __shared__ __align__(16) char smem[LDS_TOT];
  const int b    = blockIdx.x;
  const int tid  = threadIdx.x;
  const int lane = tid & 63;
  const int wid  = tid >> 6;      // 16 waves
  const int g    = lane >> 4;     // 4 quarter-wave groups
  const int ln   = lane & 15;

  // ---------------- Phase 0: stage X, W (bf16) + biases (f32) into LDS ----
  {
    const float4* xg = (const float4*)(x + (size_t)b * (256 * 64));
#pragma unroll
    for (int i = 0; i < 4; ++i) {
      int idx = tid + i * 1024;              // 4096 float4 total
      float4 v = xg[idx];
      int e = idx * 4;
      int t = e >> 6, c = e & 63;            // c multiple of 4
      u32x2 p;
      p.x = cvt_pk_bf16(v.x, v.y);
      p.y = cvt_pk_bf16(v.z, v.w);
      *(u32x2*)(smem + LDS_XQ + swz128(t, c * 2)) = p;
    }
#pragma unroll
    for (int i = 0; i < 3; ++i) {
      int idx = tid + i * 1024;              // 3072 float4 total (3 matrices)
      int mat = idx >> 10;
      int rem = idx & 1023;
      const float4* wg = (const float4*)(mat == 0 ? Wq : (mat == 1 ? Wk : Wv));
      float4 v = wg[rem];
      int e = rem * 4;
      int h = e >> 6, c = e & 63;
      u32x2 p;
      p.x = cvt_pk_bf16(v.x, v.y);
      p.y = cvt_pk_bf16(v.z, v.w);
      *(u32x2*)(smem + LDS_W + mat * 8192 + swz128(h, c * 2)) = p;
    }
    if (tid < 192) {
      float v = (tid < 64) ? bq[tid] : (tid < 128) ? bk[tid - 64] : bv[tid - 128];
      ((float*)(smem + LDS_BIAS))[tid] = v;
    }
  }
  __syncthreads();

  // ---------------- Phase 1: projections (each wave owns 16 rows) ---------
  const int rowbase = wid * 16;

  // X fragments for own rows: serve as A (for V) and as B (for Q^T,K^T).
  bf16x8 xf[2];
#pragma unroll
  for (int ks = 0; ks < 2; ++ks) {
    int t = rowbase + ln;
    u32x4 u = *(const u32x4*)(smem + LDS_XQ + swz128(t, (ks * 32 + g * 8) * 2));
    xf[ks] = __builtin_bit_cast(bf16x8, u);
  }

  // Q and K via W·X^T: acc D[h][t] -> contiguous b64 stores of row-major [t][h].
#pragma unroll
  for (int m = 0; m < 2; ++m) {              // 0 -> Q (scaled 1/8), 1 -> K
    const int wb = LDS_W + m * 8192;
#pragma unroll
    for (int mt = 0; mt < 4; ++mt) {
      float4 bb = *(const float4*)(smem + LDS_BIAS + (m * 64 + mt * 16 + g * 4) * 4);
      f32x4 acc = {0.f, 0.f, 0.f, 0.f};
#pragma unroll
      for (int ks = 0; ks < 2; ++ks) {
        int h = mt * 16 + ln;
        u32x4 u = *(const u32x4*)(smem + wb + swz128(h, (ks * 32 + g * 8) * 2));
        acc = __builtin_amdgcn_mfma_f32_16x16x32_bf16(
                __builtin_bit_cast(bf16x8, u), xf[ks], acc, 0, 0, 0);
      }
      int t  = rowbase + ln;
      int h0 = mt * 16 + g * 4;
      float s = (m == 0) ? 0.125f : 1.0f;
      u32x2 p;
      p.x = cvt_pk_bf16((acc[0] + bb.x) * s, (acc[1] + bb.y) * s);
      p.y = cvt_pk_bf16((acc[2] + bb.z) * s, (acc[3] + bb.w) * s);
      char* dst = smem + ((m == 0) ? LDS_XQ : LDS_K);  // Q overwrites X rows
      *(u32x2*)(dst + swz128(t, h0 * 2)) = p;
    }
  }

  // V via X·Wv^T: acc D[t][h] -> contiguous b64 stores of transposed Vt[h][t].
#pragma unroll
  for (int nf = 0; nf < 4; ++nf) {
    int h = nf * 16 + ln;
    float bvv = ((const float*)(smem + LDS_BIAS))[128 + h];
    f32x4 acc = {0.f, 0.f, 0.f, 0.f};
#pragma unroll
    for (int ks = 0; ks < 2; ++ks) {
      u32x4 u = *(const u32x4*)(smem + LDS_W + 2 * 8192 + swz128(h, (ks * 32 + g * 8) * 2));
      acc = __builtin_amdgcn_mfma_f32_16x16x32_bf16(
              xf[ks], __builtin_bit_cast(bf16x8, u), acc, 0, 0, 0);
    }
    int t0 = rowbase + g * 4;
    u32x2 p;
    p.x = cvt_pk_bf16(acc[0] + bvv, acc[1] + bvv);
    p.y = cvt_pk_bf16(acc[2] + bvv, acc[3] + bvv);
    *(u32x2*)(smem + LDS_VT + swz512(h, t0 * 2)) = p;
  }
  __syncthreads();

  // ---------------- Phase 2: flash attention (wave w: rows [16w,16w+16)) --
  // Swapped QK^T: S = mfma(K, Q) -> lane owns q-row (q = rowbase+ln),
  // 16 key-scores in-register; softmax reduce = in-lane + 2 shuffles.
  bf16x8 qa[2];
#pragma unroll
  for (int ks = 0; ks < 2; ++ks) {
    int t = rowbase + ln;
    u32x4 u = *(const u32x4*)(smem + LDS_XQ + swz128(t, (ks * 32 + g * 8) * 2));
    qa[ks] = __builtin_bit_cast(bf16x8, u);
  }

  float mrun = -1e30f, lrun = 0.f;
  f32x4 oacc[4];
#pragma unroll
  for (int nf = 0; nf < 4; ++nf)
    oacc[nf] = (f32x4){0.f, 0.f, 0.f, 0.f};

  const int jmax = rowbase >> 6;
  for (int jt = 0; jt <= jmax; ++jt) {
    // S = K·Q^T (scale pre-folded into Q): s[nk][d] = S[key][q],
    // key = jt*64 + nk*16 + g*4 + d, q = rowbase + ln.
    f32x4 s[4];
#pragma unroll
    for (int nk = 0; nk < 4; ++nk)
      s[nk] = (f32x4){0.f, 0.f, 0.f, 0.f};
#pragma unroll
    for (int ks = 0; ks < 2; ++ks) {
      bf16x8 kb[4];
#pragma unroll
      for (int nk = 0; nk < 4; ++nk) {
        int key = jt * 64 + nk * 16 + ln;
        u32x4 u = *(const u32x4*)(smem + LDS_K + swz128(key, (ks * 32 + g * 8) * 2));
        kb[nk] = __builtin_bit_cast(bf16x8, u);
      }
#pragma unroll
      for (int nk = 0; nk < 4; ++nk)
        s[nk] = __builtin_amdgcn_mfma_f32_16x16x32_bf16(kb[nk], qa[ks], s[nk], 0, 0, 0);
    }
    // causal mask: only the diagonal tile is partial
    if (jt == jmax) {
      int q_abs = rowbase + ln;
#pragma unroll
      for (int nk = 0; nk < 4; ++nk) {
        int keybase = jt * 64 + nk * 16 + g * 4;
#pragma unroll
        for (int d = 0; d < 4; ++d)
          s[nk][d] = (keybase + d > q_abs) ? -1e30f : s[nk][d];
      }
    }
    // online softmax: per-lane scalar state (lane owns q-row = rowbase+ln)
    {
      f32x4 m4;
#pragma unroll
      for (int d = 0; d < 4; ++d)
        m4[d] = fmaxf(fmaxf(s[0][d], s[1][d]), fmaxf(s[2][d], s[3][d]));
      float mx = fmaxf(fmaxf(m4[0], m4[1]), fmaxf(m4[2], m4[3]));
      mx = fmaxf(mx, __shfl_xor(mx, 16));
      mx = fmaxf(mx, __shfl_xor(mx, 32));
      float mn = fmaxf(mrun, mx);
      float a  = __expf(mrun - mn);
      mrun = mn;
      float sum = 0.f;
#pragma unroll
      for (int nk = 0; nk < 4; ++nk)
#pragma unroll
        for (int d = 0; d < 4; ++d) {
          float p = __expf(s[nk][d] - mn);
          s[nk][d] = p;
          sum += p;
        }
      sum += __shfl_xor(sum, 16);
      sum += __shfl_xor(sum, 32);
      lrun = lrun * a + sum;
      // rescale O: oacc rows are q = g*4+d -> fetch that row's factor
#pragma unroll
      for (int d = 0; d < 4; ++d) {
        float ad = __shfl(a, g * 4 + d);
#pragma unroll
        for (int nf = 0; nf < 4; ++nf)
          oacc[nf][d] *= ad;
      }
      // P store: key-contiguous in-lane -> packed b64 per nk
#pragma unroll
      for (int nk = 0; nk < 4; ++nk) {
        u32x2 p;
        p.x = cvt_pk_bf16(s[nk][0], s[nk][1]);
        p.y = cvt_pk_bf16(s[nk][2], s[nk][3]);
        *(u32x2*)(smem + LDS_XQ + swz128(rowbase + ln, (nk * 16 + g * 4) * 2)) = p;
      }
    }
    // O += P·V
#pragma unroll
    for (int ks = 0; ks < 2; ++ks) {
      bf16x8 pa;
      {
        int t = rowbase + ln;
        u32x4 u = *(const u32x4*)(smem + LDS_XQ + swz128(t, (ks * 32 + g * 8) * 2));
        pa = __builtin_bit_cast(bf16x8, u);
      }
      bf16x8 vb[4];
#pragma unroll
      for (int nf = 0; nf < 4; ++nf) {
        int h = nf * 16 + ln;
        int key0 = jt * 64 + ks * 32 + g * 8;
        u32x4 u = *(const u32x4*)(smem + LDS_VT + swz512(h, key0 * 2));
        vb[nf] = __builtin_bit_cast(bf16x8, u);
      }
#pragma unroll
      for (int nf = 0; nf < 4; ++nf)
        oacc[nf] = __builtin_amdgcn_mfma_f32_16x16x32_bf16(pa, vb[nf], oacc[nf], 0, 0, 0);
    }
  }

  // ---------------- Epilogue: O /= l, store fp32 --------------------------
  float* og = out + (size_t)b * (256 * 64);
  {
    float linv = 1.0f / lrun;
    float inv[4];
#pragma unroll
    for (int d = 0; d < 4; ++d) inv[d] = __shfl(linv, g * 4 + d);
#pragma unroll
    for (int nf = 0; nf < 4; ++nf)
#pragma unroll
      for (int d = 0; d < 4; ++d) {
        int t = rowbase + g * 4 + d;
        og[t * 64 + nf * 16 + ln] = oacc[nf][d] * inv[d];
      }
  }
}

extern "C" void kernel_launch(void* const* d_in, const int* in_sizes, int n_in,
                              void* d_out, int out_size, void* d_ws, size_t ws_size,
                              hipStream_t stream) {
  (void)in_sizes; (void)n_in; (void)d_ws; (void)ws_size; (void)out_size;
  const float* x  = (const float*)d_in[0];
  const float* Wq = (const float*)d_in[1];
  const float* bq = (const float*)d_in[2];
  const float* Wk = (const float*)d_in[3];
  const float* bk = (const float*)d_in[4];
  const float* Wv = (const float*)d_in[5];
  const float* bv = (const float*)d_in[6];
  float* out = (float*)d_out;
  hipLaunchKernelGGL(head_fused, dim3(1024), dim3(1024), 0, stream,
                     x, Wq, bq, Wk, bk, Wv, bv, out);
}